// Round 3
// baseline (390.347 us; speedup 1.0000x reference)
//
#include <hip/hip_runtime.h>

// Problem constants (B,S,D,H from reference)
#define B_ 2
#define S_ 2048
#define D_ 1024
#define H_ 16
#define DK_ 64
#define M_ (B_ * S_)      // 4096 rows in the projection GEMMs

typedef __bf16 bf16;
typedef __attribute__((ext_vector_type(8))) __bf16 bf16x8;
typedef __attribute__((ext_vector_type(4))) __bf16 bf16x4;
typedef __attribute__((ext_vector_type(4))) float f32x4;

static __device__ __forceinline__ bf16x8 ld8(const bf16* p) {
    return *(const bf16x8*)p;   // 16B aligned by construction
}

// ---------------------------------------------------------------------------
// Elementwise fp32 -> bf16 for the 3 X inputs (into d_out scratch) and the
// 4 weight matrices (into ws). Block mapping: 3*2048 X-blocks + 4*512 W-blocks.
// ---------------------------------------------------------------------------
__global__ __launch_bounds__(256)
void cvt_all(const float* __restrict__ xq, const float* __restrict__ xk,
             const float* __restrict__ xv, const float* __restrict__ wq,
             const float* __restrict__ wk, const float* __restrict__ wv,
             const float* __restrict__ wo, bf16* __restrict__ xqo,
             bf16* __restrict__ xko, bf16* __restrict__ xvo,
             bf16* __restrict__ wqo, bf16* __restrict__ wko,
             bf16* __restrict__ wvo, bf16* __restrict__ woo)
{
    const int bx = blockIdx.x;
    const float* s; bf16* d; size_t base;
    if (bx < 6144) {
        int a = bx >> 11;
        s = (a == 0) ? xq : (a == 1) ? xk : xv;
        d = (a == 0) ? xqo : (a == 1) ? xko : xvo;
        base = (size_t)(bx & 2047) * 2048;
    } else {
        int a = (bx - 6144) >> 9;
        s = (a == 0) ? wq : (a == 1) ? wk : (a == 2) ? wv : wo;
        d = (a == 0) ? wqo : (a == 1) ? wko : (a == 2) ? wvo : woo;
        base = (size_t)((bx - 6144) & 511) * 2048;
    }
    size_t i = base + (size_t)threadIdx.x * 8;
    f32x4 a4 = *(const f32x4*)(s + i);
    f32x4 b4 = *(const f32x4*)(s + i + 4);
    bf16x8 r;
    r[0]=(bf16)a4[0]; r[1]=(bf16)a4[1]; r[2]=(bf16)a4[2]; r[3]=(bf16)a4[3];
    r[4]=(bf16)b4[0]; r[5]=(bf16)b4[1]; r[6]=(bf16)b4[2]; r[7]=(bf16)b4[3];
    *(bf16x8*)(d + i) = r;
}

// ---------------------------------------------------------------------------
// 128x128-tile bf16 GEMM, LDS-staged, 2-barrier K-loop.
// out_mode: 0 = bf16 head-split (B,H,S,DK);  1 = fp32 flat (M,N);
//           2 = bf16 TRANSPOSED head-split (B,H,DK,S)  [for V^T]
// a_headsplit: A element (m,k) at ((b*H+h)*S+s)*DK+dk (ctx layout).
// scale: applied after bias (Q gemm folds the 1/sqrt(DK)=0.125 softmax scale
//        -- exact power of two, so scores are bit-identical to scaling later).
// ---------------------------------------------------------------------------
__global__ __launch_bounds__(256)
void gemm128(const bf16* __restrict__ A, const bf16* __restrict__ W,
             const float* __restrict__ bias, void* __restrict__ out,
             int a_headsplit, int out_mode, float scale)
{
    const int m0 = blockIdx.x * 128, n0 = blockIdx.y * 128;
    const int tid = threadIdx.x;
    const int wv = tid >> 6, lane = tid & 63, quad = lane >> 4, l16 = lane & 15;
    const int wr = (wv >> 1) * 64, wc = (wv & 1) * 64;

    __shared__ bf16 As[128 * 32];
    __shared__ bf16 Bs[128 * 32];

    f32x4 acc[4][4];
#pragma unroll
    for (int i = 0; i < 4; ++i)
#pragma unroll
        for (int j = 0; j < 4; ++j) acc[i][j] = f32x4{0.f, 0.f, 0.f, 0.f};

    const int srow = tid >> 2;
    const int scol = (tid & 3) * 8;

    for (int k0 = 0; k0 < D_; k0 += 32) {
        bf16x8 av[2], bw[2];
#pragma unroll
        for (int c = 0; c < 2; ++c) {
            const int row = c * 64 + srow;
            const int k   = k0 + scol;
            const bf16* ap;
            if (a_headsplit) {
                int m = m0 + row, bb = m >> 11, ss = m & (S_ - 1);
                int hh = k >> 6, dd = k & (DK_ - 1);
                ap = A + (((size_t)(bb * H_ + hh) * S_ + ss) * DK_ + dd);
            } else {
                ap = A + (size_t)(m0 + row) * D_ + k;
            }
            av[c] = ld8(ap);
            bw[c] = ld8(W + (size_t)(n0 + row) * D_ + k);
        }
        __syncthreads();
#pragma unroll
        for (int c = 0; c < 2; ++c) {
            const int e = c * 2048 + tid * 8;
            *(bf16x8*)(As + e) = av[c];
            *(bf16x8*)(Bs + e) = bw[c];
        }
        __syncthreads();

        bf16x8 af[4], bfr[4];
#pragma unroll
        for (int i = 0; i < 4; ++i)
            af[i] = *(const bf16x8*)(As + (wr + i*16 + l16) * 32 + quad * 8);
#pragma unroll
        for (int j = 0; j < 4; ++j)
            bfr[j] = *(const bf16x8*)(Bs + (wc + j*16 + l16) * 32 + quad * 8);
#pragma unroll
        for (int i = 0; i < 4; ++i)
#pragma unroll
            for (int j = 0; j < 4; ++j)
                acc[i][j] = __builtin_amdgcn_mfma_f32_16x16x32_bf16(
                    af[i], bfr[j], acc[i][j], 0, 0, 0);
    }

#pragma unroll
    for (int i = 0; i < 4; ++i)
#pragma unroll
        for (int j = 0; j < 4; ++j) {
            const int nn = n0 + wc + j*16 + l16;
            const float bvv = bias[nn];
            const int mm0 = m0 + wr + i*16 + quad*4;   // 4-aligned, same b
            if (out_mode == 2) {
                // V^T: (B,H,DK,S); 4 consecutive tokens -> one 8B store
                bf16x4 pk;
#pragma unroll
                for (int r = 0; r < 4; ++r)
                    pk[r] = (bf16)((acc[i][j][r] + bvv) * scale);
                int bb = mm0 >> 11, ss = mm0 & (S_ - 1);
                int hh = nn >> 6,  dd = nn & (DK_ - 1);
                *(bf16x4*)((bf16*)out +
                    ((size_t)(bb * H_ + hh) * DK_ + dd) * S_ + ss) = pk;
            } else {
#pragma unroll
                for (int r = 0; r < 4; ++r) {
                    const int mm = mm0 + r;
                    float v = (acc[i][j][r] + bvv) * scale;
                    if (out_mode == 1) {
                        ((float*)out)[(size_t)mm * D_ + nn] = v;
                    } else {
                        int bb = mm >> 11, ss = mm & (S_ - 1);
                        int hh = nn >> 6, dd = nn & (DK_ - 1);
                        ((bf16*)out)[((size_t)(bb * H_ + hh) * S_ + ss) * DK_ + dd] = (bf16)v;
                    }
                }
            }
        }
}

// ---------------------------------------------------------------------------
// Context + softmax denominators, fused. 1D grid, XCD-swizzled so each XCD
// owns 4 complete (h,b) groups (all 32 q-tiles) -> K/V (512KB/group) stay
// L2-resident on that XCD instead of being re-fetched by all 8.
// Per block: wave w owns j in [512w, 512w+512), processed in 32-j chunks,
// with the NEXT chunk's K fragments prefetched at the top of each iteration
// (latency hidden under the current chunk's exp+PV), and V loads hoisted
// above the QK/exp block (independent of it).
// Swapped QK^T: s = mfma(K,Q) puts P[j = quad*4+r][q = l16] in registers.
// PV uses mfma_f32_16x16x32_bf16 with a CUSTOM k->j bijection
//   k = quad*8 + t*4 + r  <->  j = t*16 + quad*4 + r     (t = j-tile 0/1)
// (legal: MFMA K-dim is a pure sum) matching the P register layout exactly,
// so no P transpose / LDS staging at all. P~ kept UNNORMALIZED; row-sums L
// accumulated alongside; normalization once in the epilogue. Writes Li for
// attn_weights.
// ---------------------------------------------------------------------------
__global__ __launch_bounds__(256)
void attn_ctx(const bf16* __restrict__ Q, const bf16* __restrict__ K,
              const bf16* __restrict__ Vt, float* __restrict__ Li,
              bf16* __restrict__ ctxOut)
{
    // XCD swizzle: bid%8 = XCD (empirical RR dispatch); each XCD gets 128
    // consecutive semantic indices = 4 full (h,b) groups. Bijective on 1024.
    const int bid = blockIdx.x;
    const int l   = (bid & 7) * 128 + (bid >> 3);
    const int q0  = (l & 31) * 64;
    const int h   = (l >> 5) & 15;
    const int b   = l >> 9;

    const int tid = threadIdx.x;
    const int wv = tid >> 6, lane = tid & 63, quad = lane >> 4, l16 = lane & 15;

    __shared__ float ctxp[4][64 * 17 + 16];   // [wv][dk*17+q]  17.7 KB
    __shared__ float wp[4][4][16];            // per-wave L partials
    __shared__ float linvs[4][16];            // 1/L per (qt, q)

    const size_t hb = (size_t)(b * H_ + h) * S_;
    bf16x8 qf[4][2];
#pragma unroll
    for (int qt = 0; qt < 4; ++qt) {
        const bf16* qrow = Q + (hb + q0 + qt*16 + l16) * DK_;
        qf[qt][0] = ld8(qrow + quad*8);
        qf[qt][1] = ld8(qrow + 32 + quad*8);
    }
    const bf16* Kb  = K  + hb * DK_;
    const bf16* Vtb = Vt + hb * DK_;   // (B,H,DK,S): row d at Vtb + d*S

    f32x4 cacc[4][4];   // [db][qt]  C[dk = db*16+quad*4+r][q = l16]
#pragma unroll
    for (int db = 0; db < 4; ++db)
#pragma unroll
        for (int qt = 0; qt < 4; ++qt) cacc[db][qt] = f32x4{0.f,0.f,0.f,0.f};
    float lsum[4] = {0.f, 0.f, 0.f, 0.f};

    const int jbase = wv * 512;

    // prefetch chunk 0's K fragments
    bf16x8 nk0a, nk0b, nk1a, nk1b;
    {
        const bf16* kr0 = Kb + (size_t)(jbase + l16) * DK_ + quad*8;
        const bf16* kr1 = Kb + (size_t)(jbase + 16 + l16) * DK_ + quad*8;
        nk0a = ld8(kr0); nk0b = ld8(kr0 + 32);
        nk1a = ld8(kr1); nk1b = ld8(kr1 + 32);
    }

    for (int jc = 0; jc < 16; ++jc) {
        const int j0 = jbase + jc * 32;
        const bf16x8 kf0a = nk0a, kf0b = nk0b, kf1a = nk1a, kf1b = nk1b;
        {   // prefetch next chunk's K ((jc+1)&15: branchless; last iter
            // harmlessly re-reads chunk 0)
            const int jn = jbase + ((jc + 1) & 15) * 32;
            const bf16* nr0 = Kb + (size_t)(jn + l16) * DK_ + quad*8;
            const bf16* nr1 = Kb + (size_t)(jn + 16 + l16) * DK_ + quad*8;
            nk0a = ld8(nr0); nk0b = ld8(nr0 + 32);
            nk1a = ld8(nr1); nk1b = ld8(nr1 + 32);
        }
        // V loads hoisted: independent of QK/exp, consumed only by PV below
        bf16x8 va[4];
#pragma unroll
        for (int db = 0; db < 4; ++db) {
            const bf16* vr = Vtb + (size_t)(db*16 + l16) * S_ + j0 + quad*4;
            bf16x4 vlo = *(const bf16x4*)vr;         // j = j0 + quad*4 + 0..3
            bf16x4 vhi = *(const bf16x4*)(vr + 16);  // j = j0+16 + quad*4+0..3
            va[db] = __builtin_shufflevector(vlo, vhi, 0,1,2,3,4,5,6,7);
        }

        bf16x8 pa[4];
#pragma unroll
        for (int qt = 0; qt < 4; ++qt) {
            f32x4 z0 = {0.f,0.f,0.f,0.f}, z1 = {0.f,0.f,0.f,0.f};
            z0 = __builtin_amdgcn_mfma_f32_16x16x32_bf16(kf0a, qf[qt][0], z0, 0, 0, 0);
            f32x4 s0 = __builtin_amdgcn_mfma_f32_16x16x32_bf16(kf0b, qf[qt][1], z0, 0, 0, 0);
            z1 = __builtin_amdgcn_mfma_f32_16x16x32_bf16(kf1a, qf[qt][0], z1, 0, 0, 0);
            f32x4 s1 = __builtin_amdgcn_mfma_f32_16x16x32_bf16(kf1b, qf[qt][1], z1, 0, 0, 0);
            // Q pre-scaled by 0.125 in its projection; same clamp as before
            float e0 = __expf(fminf(s0[0], 60.f));
            float e1 = __expf(fminf(s0[1], 60.f));
            float e2 = __expf(fminf(s0[2], 60.f));
            float e3 = __expf(fminf(s0[3], 60.f));
            float e4 = __expf(fminf(s1[0], 60.f));
            float e5 = __expf(fminf(s1[1], 60.f));
            float e6 = __expf(fminf(s1[2], 60.f));
            float e7 = __expf(fminf(s1[3], 60.f));
            lsum[qt] += ((e0 + e1) + (e2 + e3)) + ((e4 + e5) + (e6 + e7));
            bf16x8 p;
            p[0]=(bf16)e0; p[1]=(bf16)e1; p[2]=(bf16)e2; p[3]=(bf16)e3;
            p[4]=(bf16)e4; p[5]=(bf16)e5; p[6]=(bf16)e6; p[7]=(bf16)e7;
            pa[qt] = p;
        }
#pragma unroll
        for (int db = 0; db < 4; ++db)
#pragma unroll
            for (int qt = 0; qt < 4; ++qt)
                cacc[db][qt] = __builtin_amdgcn_mfma_f32_16x16x32_bf16(
                    va[db], pa[qt], cacc[db][qt], 0, 0, 0);
    }

    // L: reduce across quads (lanes sharing l16), then across waves via LDS
#pragma unroll
    for (int qt = 0; qt < 4; ++qt) {
        lsum[qt] += __shfl_xor(lsum[qt], 16);
        lsum[qt] += __shfl_xor(lsum[qt], 32);
    }
    if (lane < 16) {
#pragma unroll
        for (int qt = 0; qt < 4; ++qt) wp[wv][qt][lane] = lsum[qt];
    }
    __syncthreads();
    if (tid < 64) {
        int qt = tid >> 4, row = tid & 15;
        float L = wp[0][qt][row] + wp[1][qt][row] + wp[2][qt][row] + wp[3][qt][row];
        Li[hb + q0 + qt*16 + row] = L;
        linvs[qt][row] = 1.0f / fmaxf(L, 1e-30f);
    }

    // cross-wave ctx reduce + normalize + write, one q-tile at a time
#pragma unroll
    for (int qt = 0; qt < 4; ++qt) {
        __syncthreads();   // also orders linvs writes before first combine
#pragma unroll
        for (int db = 0; db < 4; ++db)
#pragma unroll
            for (int r = 0; r < 4; ++r)
                ctxp[wv][(db*16 + quad*4 + r) * 17 + l16] = cacc[db][qt][r];
        __syncthreads();
        {
            const int q  = tid >> 4;          // 0..15
            const int d0 = (tid & 15) * 4;    // 0,4,..,60
            const float lv = linvs[qt][q];
            bf16x4 pk;
#pragma unroll
            for (int i = 0; i < 4; ++i) {
                const int e = (d0 + i) * 17 + q;
                pk[i] = (bf16)((ctxp[0][e] + ctxp[1][e] + ctxp[2][e] + ctxp[3][e]) * lv);
            }
            *(bf16x4*)(ctxOut + (hb + q0 + qt*16 + q) * DK_ + d0) = pk;
        }
    }
}

// ---------------------------------------------------------------------------
// Head-mean attention weights. 1D grid, XCD-swizzled so each XCD owns one
// j-chunk (K rows for all 16 heads = 1MB -> L2-resident); Q streams.
// Swapped QK^T: lane holds 4 CONSECUTIVE j for its q -> f32x4 stores, and
// linv is one value per (h,q) (hoisted; 1/H folded in).
// ---------------------------------------------------------------------------
__global__ __launch_bounds__(256)
void attn_weights(const bf16* __restrict__ Q, const bf16* __restrict__ K,
                  const float* __restrict__ Li, float* __restrict__ attnOut)
{
    // 512 blocks: l = q-tile (32) x b (2) x j-chunk (8); each XCD gets 64
    // consecutive l = one j-chunk, both b. Bijective.
    const int bid = blockIdx.x;
    const int l   = (bid & 7) * 64 + (bid >> 3);
    const int q0  = (l & 31) * 64;
    const int b   = (l >> 5) & 1;
    const int j0  = (l >> 6) * 256;

    const int tid = threadIdx.x;
    const int wv = tid >> 6, lane = tid & 63, quad = lane >> 4, l16 = lane & 15;

    __shared__ float linv[H_][64];
#pragma unroll
    for (int i = 0; i < 4; ++i) {
        int idx = tid * 4 + i;
        int hh = idx >> 6, row = idx & 63;
        linv[hh][row] = (1.0f / H_) /
            fmaxf(Li[(size_t)(b * H_ + hh) * S_ + q0 + row], 1e-30f);
    }
    __syncthreads();

    f32x4 asum[4][4];
#pragma unroll
    for (int qt = 0; qt < 4; ++qt)
#pragma unroll
        for (int t = 0; t < 4; ++t) asum[qt][t] = f32x4{0.f,0.f,0.f,0.f};

    for (int h = 0; h < H_; ++h) {
        const size_t hb = (size_t)(b * H_ + h) * S_;
        bf16x8 qf[4][2];
        float lv[4];
#pragma unroll
        for (int qt = 0; qt < 4; ++qt) {
            const bf16* qrow = Q + (hb + q0 + qt*16 + l16) * DK_;
            qf[qt][0] = ld8(qrow + quad*8);
            qf[qt][1] = ld8(qrow + 32 + quad*8);
            lv[qt] = linv[h][qt*16 + l16];
        }
        const bf16* Kb = K + hb * DK_;
#pragma unroll
        for (int t = 0; t < 4; ++t) {
            const int jl = j0 + wv*64 + t*16;
            const bf16* krow = Kb + (size_t)(jl + l16) * DK_;
            bf16x8 kfa = ld8(krow + quad*8), kfb = ld8(krow + 32 + quad*8);
#pragma unroll
            for (int qt = 0; qt < 4; ++qt) {
                f32x4 z = {0.f,0.f,0.f,0.f};
                z = __builtin_amdgcn_mfma_f32_16x16x32_bf16(kfa, qf[qt][0], z, 0, 0, 0);
                f32x4 s = __builtin_amdgcn_mfma_f32_16x16x32_bf16(kfb, qf[qt][1], z, 0, 0, 0);
#pragma unroll
                for (int r = 0; r < 4; ++r)
                    asum[qt][t][r] += __expf(fminf(s[r], 60.f)) * lv[qt];
            }
        }
    }
#pragma unroll
    for (int qt = 0; qt < 4; ++qt)
#pragma unroll
        for (int t = 0; t < 4; ++t)
            *(f32x4*)(attnOut + ((size_t)b * S_ + q0 + qt*16 + l16) * S_
                      + j0 + wv*64 + t*16 + quad*4) = asum[qt][t];
}

// ---------------------------------------------------------------------------
extern "C" void kernel_launch(void* const* d_in, const int* in_sizes, int n_in,
                              void* d_out, int out_size, void* d_ws, size_t ws_size,
                              hipStream_t stream)
{
    (void)in_sizes; (void)n_in; (void)out_size; (void)ws_size;

    const float* query = (const float*)d_in[0];
    const float* key_t = (const float*)d_in[1];
    const float* value = (const float*)d_in[2];
    const float* Wq = (const float*)d_in[3];
    const float* bq = (const float*)d_in[4];
    const float* Wk = (const float*)d_in[5];
    const float* bk = (const float*)d_in[6];
    const float* Wv = (const float*)d_in[7];
    const float* bv = (const float*)d_in[8];
    const float* Wo = (const float*)d_in[9];
    const float* bo = (const float*)d_in[10];

    float* out     = (float*)d_out;                  // (B,S,D) fp32
    float* attnOut = out + (size_t)B_ * S_ * D_;     // (B,S,S) fp32

    const size_t nX = (size_t)B_ * S_ * D_;
    const size_t nW = (size_t)D_ * D_;

    // d_out doubles as scratch for bf16 X-converts (dead before overwrites)
    bf16* Xqb = (bf16*)d_out;
    bf16* Xkb = Xqb + nX;
    bf16* Xvb = Xkb + nX;

    // ws: Qh,Kh,VtH (25.2MB) + Wob (2.1MB) + Li (0.26MB) + [Wqb/Wkb/Wvb
    // overlaid by CtxH (8.4MB) -- W converts are dead before attn_ctx runs].
    bf16* Qh  = (bf16*)d_ws;
    bf16* Kh  = Qh + nX;
    bf16* VtH = Kh + nX;                             // V^T (B,H,DK,S)
    bf16* Wob = VtH + nX;
    float* Li = (float*)(Wob + nW);
    bf16* Wqb = (bf16*)(Li + (size_t)B_ * H_ * S_);
    bf16* Wkb = Wqb + nW;
    bf16* Wvb = Wkb + nW;
    bf16* CtxH = Wqb;                                // overlays dead W converts

    cvt_all<<<8192, 256, 0, stream>>>(query, key_t, value, Wq, Wk, Wv, Wo,
                                      Xqb, Xkb, Xvb, Wqb, Wkb, Wvb, Wob);
    dim3 gg(M_/128, D_/128);
    // Q pre-scaled by 1/sqrt(DK) = 0.125 (exact pow2: scores bit-identical)
    gemm128<<<gg, 256, 0, stream>>>(Xqb, Wqb, bq, Qh, 0, 0, 0.125f);
    gemm128<<<gg, 256, 0, stream>>>(Xkb, Wkb, bk, Kh, 0, 0, 1.0f);
    gemm128<<<gg, 256, 0, stream>>>(Xvb, Wvb, bv, VtH, 0, 2, 1.0f);   // V^T
    attn_ctx    <<<1024, 256, 0, stream>>>(Qh, Kh, VtH, Li, CtxH);
    attn_weights<<<512, 256, 0, stream>>>(Qh, Kh, Li, attnOut);
    gemm128<<<gg, 256, 0, stream>>>(CtxH, Wob, bo, out, 1, 1, 1.0f);
}